// Round 8
// baseline (825.386 us; speedup 1.0000x reference)
//
#include <hip/hip_runtime.h>
#include <math.h>

#define D_OPT   128
#define N_SIM   2048
#define M_STEPS 64
#define HID     64

// Round 14: ILP-depth test (4 in-flight ladders) + register trims.
// Falsified: TLP (R9b), barrier vmcnt drain (R11), ladder count (R12 — kept
// unroll 2, so depth never exceeded 2!), phase mixing (R13). Surviving model:
// ~300cy serial chains, ~7 concurrent/SIMD -> ~30% VALU bubbles when all
// chains sit in MFMA-result latency. R14: FULL unroll of the 4-tile loop
// (4 chains/wave, ~13/SIMD). Offsetting reg trims:
//  - L3 via 4x chained mfma 16x16x16f16 (A3 16->8 regs). B-fragment per gt
//    = that gt's own acc pairs (slot k=q*4+e carries h2[gt*16+4q+e]).
//  - b3 as L3 C-splat cinit3 (+4 regs, -4 update VALU).
// Pipeline otherwise unchanged (validated): L1 = mfma 16x16x16f16 (bias in
// k-slot 3 x packed 1.0); L2 = 2x mfma 16x16x32 (baked k-permutation).

typedef _Float16 f16x8 __attribute__((ext_vector_type(8)));
typedef _Float16 f16x4 __attribute__((ext_vector_type(4)));
typedef _Float16 f16x2 __attribute__((ext_vector_type(2)));
typedef float    f32x4 __attribute__((ext_vector_type(4)));
typedef unsigned int u32;
typedef u32 u32x2 __attribute__((ext_vector_type(2)));
typedef u32 u32x4 __attribute__((ext_vector_type(4)));

__device__ __forceinline__ u32 pk2u(float a, float b) {
#if __has_builtin(__builtin_amdgcn_cvt_pkrtz)
    return __builtin_bit_cast(u32, __builtin_amdgcn_cvt_pkrtz(a, b));
#else
    f16x2 p; p[0] = (_Float16)a; p[1] = (_Float16)b;
    return __builtin_bit_cast(u32, p);
#endif
}

__device__ __forceinline__ u32 pk_relu_cvt(float a, float b) {
    f16x2 p = __builtin_bit_cast(f16x2, pk2u(a, b));
    const f16x2 z = { (_Float16)0.0f, (_Float16)0.0f };
#if __has_builtin(__builtin_elementwise_max)
    p = __builtin_elementwise_max(p, z);
#else
    p[0] = p[0] > z[0] ? p[0] : z[0];
    p[1] = p[1] > z[1] ? p[1] : z[1];
#endif
    return __builtin_bit_cast(u32, p);
}

__global__ __launch_bounds__(256, 4) void nsde_kernel(
    const float* __restrict__ S0p, const float* __restrict__ Kp,
    const float* __restrict__ Tp,  const float* __restrict__ rfp,
    const float* __restrict__ V0p, const float* __restrict__ rhop,
    const float* __restrict__ Z1,  const float* __restrict__ Z2r,
    const float* __restrict__ W1,  const float* __restrict__ B1,
    const float* __restrict__ W2,  const float* __restrict__ B2,
    const float* __restrict__ W3,  const float* __restrict__ B3,
    float* __restrict__ out)
{
    __shared__ float nvp[2][4][64];   // [buf][net][element] = o+b3, 2 KB
    __shared__ u32x2 pkx[4][64];      // [wave][element] {pk(S,V), pk(dt*s,1)}, 2 KB

    const int tid  = threadIdx.x;
    const int wave = tid >> 6;        // wave == net
    const int lane = tid & 63;
    const int q    = lane >> 4;
    const int mA   = lane & 15;
    const float rf = rfp[0];

    const float* w1g = W1 + wave * 256;   // [4][64]
    const float* b1g = B1 + wave * 64;
    const float* w2g = W2 + wave * 4096;  // [64][64] (h, g)
    const float* b2g = B2 + wave * 64;
    const float* w3g = W3 + wave * 64;    // [64]

    // ---------------- constant fragments (register-resident) ----------------
    // L1 (K=16): A[row=mA][k=q*4+j]; q==0 holds {wS, wV, wt, b1+rf*w_rf}.
    f16x4 A1[4];
    #pragma unroll
    for (int t = 0; t < 4; ++t) {
        f16x4 a = { (_Float16)0.0f, (_Float16)0.0f, (_Float16)0.0f, (_Float16)0.0f };
        if (q == 0) {
            const int h = t * 16 + mA;
            a[0] = (_Float16)w1g[0 * 64 + h];                       // S weight
            a[1] = (_Float16)w1g[1 * 64 + h];                       // V weight
            a[2] = (_Float16)w1g[3 * 64 + h];                       // dt*j weight
            a[3] = (_Float16)fmaf(rf, w1g[2 * 64 + h], b1g[h]);     // bias (x1.0)
        }
        A1[t] = a;
    }

    // L2 (K=32): A[row -> g=gt*16+mA][slot (kt,q*8+j) -> h1=H(kt,q*8+j)]
    f16x8 A2[4][2];
    #pragma unroll
    for (int gt = 0; gt < 4; ++gt)
        #pragma unroll
        for (int kt = 0; kt < 2; ++kt) {
            f16x8 a;
            #pragma unroll
            for (int j = 0; j < 8; ++j) {
                const int h1 = (2 * kt + (j >> 2)) * 16 + 4 * q + (j & 3);
                a[j] = (_Float16)w2g[h1 * 64 + gt * 16 + mA];
            }
            A2[gt][kt] = a;
        }

    // L3 (K=16 x4): per gt tile, row 0 = w3 slice; slot k=q*4+e carries
    // h2[gt*16 + 4q + e] (= acc pair layout of that gt's L2 output).
    f16x4 A3[4];
    #pragma unroll
    for (int gt = 0; gt < 4; ++gt) {
        f16x4 a = { (_Float16)0.0f, (_Float16)0.0f, (_Float16)0.0f, (_Float16)0.0f };
        if (mA == 0) {
            #pragma unroll
            for (int e = 0; e < 4; ++e)
                a[e] = (_Float16)w3g[gt * 16 + 4 * q + e];
        }
        A3[gt] = a;
    }

    // L2 bias C-splats (row = 4q+r); L1 uses zero C; L3 C = b3 splat.
    f32x4 cinit2[4];
    #pragma unroll
    for (int t = 0; t < 4; ++t)
        #pragma unroll
        for (int r = 0; r < 4; ++r)
            cinit2[t][r] = b2g[t * 16 + 4 * q + r];
    const f32x4 zc = { 0.0f, 0.0f, 0.0f, 0.0f };
    const float b3w = B3[wave];
    const f32x4 cinit3 = { b3w, b3w, b3w, b3w };

    // ---------------- per-element state ----------------
    const int ebase = blockIdx.x * 64;
    const int d_own = (ebase + lane) & (D_OPT - 1);
    const float dt_own  = Tp[d_own] * (1.0f / (float)M_STEPS);
    const float sdt_own = sqrtf(dt_own);

    float Sreg = S0p[d_own];
    float Vreg = V0p[0];
    {
        u32x2 pk0;
        pk0[0] = pk2u(Sreg, Vreg);
        pk0[1] = pk2u(0.0f, 1.0f);    // {dt*j at step 0, bias multiplier}
        pkx[wave][lane] = pk0;
    }

    const float rho   = rhop[0];
    const float rho_c = sqrtf(1.0f - rho * rho);
    const size_t estep = (size_t)N_SIM * D_OPT;
    const float* z1p = Z1  + (size_t)ebase + (size_t)lane;
    const float* z2p = Z2r + (size_t)ebase + (size_t)lane;

    float z1c = *z1p;           // step 0 values
    float z2c = *z2p;
    z1p += estep; z2p += estep; // -> step 1

    #pragma unroll 1
    for (int s = 0; s < M_STEPS; ++s) {
        // prefetch next-step z (stays in flight across the lgkm-only barrier)
        const float z1n = *z1p;
        const float z2n = *z2p;
        const size_t adv = (s < M_STEPS - 2) ? estep : (size_t)0;
        z1p += adv; z2p += adv;

        #pragma unroll
        for (int mt = 0; mt < 4; ++mt) {
            // feature B-fragment = raw exchange word (zero VALU)
            const u32x2 pksv = pkx[wave][mt * 16 + mA];
            const f16x4 B1f = __builtin_bit_cast(f16x4, pksv);

            // L1 -> pack relu(h1) into B2 (adjacent acc pairs = baked slots)
            u32x4 b2u[2];
            #pragma unroll
            for (int t = 0; t < 4; ++t) {
                const f32x4 acc = __builtin_amdgcn_mfma_f32_16x16x16f16(
                                      A1[t], B1f, zc, 0, 0, 0);
                b2u[t >> 1][(t & 1) * 2 + 0] = pk_relu_cvt(acc[0], acc[1]);
                b2u[t >> 1][(t & 1) * 2 + 1] = pk_relu_cvt(acc[2], acc[3]);
            }
            const f16x8 B2f0 = __builtin_bit_cast(f16x8, b2u[0]);
            const f16x8 B2f1 = __builtin_bit_cast(f16x8, b2u[1]);

            // L2 -> per-gt pack relu(h2) -> chained K=16 L3 (C = b3 splat)
            f32x4 acc3 = cinit3;
            #pragma unroll
            for (int gt = 0; gt < 4; ++gt) {
                f32x4 acc = __builtin_amdgcn_mfma_f32_16x16x32_f16(
                                A2[gt][0], B2f0, cinit2[gt], 0, 0, 0);
                acc = __builtin_amdgcn_mfma_f32_16x16x32_f16(
                                A2[gt][1], B2f1, acc, 0, 0, 0);
                u32x2 b3u;
                b3u[0] = pk_relu_cvt(acc[0], acc[1]);
                b3u[1] = pk_relu_cvt(acc[2], acc[3]);
                acc3 = __builtin_amdgcn_mfma_f32_16x16x16f16(
                           A3[gt], __builtin_bit_cast(f16x4, b3u), acc3, 0, 0, 0);
            }

            // o+b3 lands in row 0 = lanes q==0, reg 0
            if (q == 0)
                nvp[s & 1][wave][mt * 16 + mA] = acc3[0];
        }

        // lgkm-only barrier: drain DS writes, sync waves, leave vmcnt in flight
        __builtin_amdgcn_sched_barrier(0);
        asm volatile("s_waitcnt lgkmcnt(0)\n\ts_barrier" ::: "memory");
        __builtin_amdgcn_sched_barrier(0);

        // ---- once-per-lane SDE update of own element e == lane ----
        {
            const float o0 = nvp[s & 1][0][lane];
            const float o1 = nvp[s & 1][1][lane];
            const float o2 = nvp[s & 1][2][lane];
            const float o3 = nvp[s & 1][3][lane];
            const float e0 = __expf(2.0f * o0);
            const float e1 = __expf(2.0f * o1);
            const float e2 = __expf(2.0f * o2);
            const float e3 = __expf(2.0f * o3);
            const float N0 = 1.0f - 2.0f / (e0 + 1.0f);
            const float N1 = 1.0f - 2.0f / (e1 + 1.0f);
            const float N2 = 1.0f - 2.0f / (e2 + 1.0f);
            const float N3 = 1.0f - 2.0f / (e3 + 1.0f);
            const float z2 = fmaf(rho, z1c, rho_c * z2c);
            const float fS = fmaf(N1 * sdt_own, z1c, N0 * dt_own);
            const float fV = fmaf(N3 * sdt_own, z2, N2 * dt_own);
            Sreg = fmaf(Sreg, fS, Sreg);
            Vreg = fmaf(Vreg, fV, Vreg);
            u32x2 pkn;
            pkn[0] = pk2u(Sreg, Vreg);
            pkn[1] = pk2u(dt_own * (float)(s + 1), 1.0f);  // next step's {dt*j, 1}
            pkx[wave][lane] = pkn;
            z1c = z1n; z2c = z2n;
        }
    }

    // ---- payoff: wave 0, lane == element ----
    if (wave == 0) {
        const float Td  = dt_own * (float)M_STEPS;
        const float pay = fmaxf(Sreg - Kp[d_own], 0.0f);
        atomicAdd(&out[d_own], __expf(-rf * Td) * pay * (1.0f / (float)N_SIM));
    }
}

extern "C" void kernel_launch(void* const* d_in, const int* in_sizes, int n_in,
                              void* d_out, int out_size, void* d_ws, size_t ws_size,
                              hipStream_t stream)
{
    const float* S0  = (const float*)d_in[0];
    const float* K   = (const float*)d_in[1];
    const float* T   = (const float*)d_in[2];
    const float* rf  = (const float*)d_in[3];
    const float* V0  = (const float*)d_in[4];
    const float* rho = (const float*)d_in[5];
    const float* Z1  = (const float*)d_in[6];
    const float* Z2r = (const float*)d_in[7];
    const float* W1  = (const float*)d_in[8];
    const float* B1  = (const float*)d_in[9];
    const float* W2  = (const float*)d_in[10];
    const float* B2  = (const float*)d_in[11];
    const float* W3  = (const float*)d_in[12];
    const float* B3  = (const float*)d_in[13];
    float* out = (float*)d_out;

    hipMemsetAsync(out, 0, (size_t)out_size * sizeof(float), stream);

    const int total = N_SIM * D_OPT;              // 262144 elements
    const int grid  = total / 64;                 // 64 elements per block
    nsde_kernel<<<grid, 256, 0, stream>>>(S0, K, T, rf, V0, rho, Z1, Z2r,
                                          W1, B1, W2, B2, W3, B3, out);
}

// Round 9
// 736.799 us; speedup vs baseline: 1.1202x; 1.1202x over previous
//
#include <hip/hip_runtime.h>
#include <math.h>

#define D_OPT   128
#define N_SIM   2048
#define M_STEPS 64
#define HID     64

// Round 15: revert to best-known structure (R11, 794us) + rcp-based tanh.
// Falsified levers: TLP (R9b +29% occ -> -5%), vmcnt drain (R11 flat),
// ladder count (R12 flat), phase mixing (R13 flat), ILP depth (R14 -5%).
// dur invariance (794-833) across all schedules => issue/latency equilibrium;
// only issued-work cuts have ever won (R8 -23%, R9b -5%). Remaining fat:
// update phase used IEEE f32 division (2.0f/(e+1)) -> v_div_scale/rcp/
// div_fmas/div_fixup (~8 ops) x4 per lane-step on the semi-serial spine.
// Replaced with v_rcp_f32 (1 ulp; tanh output err ~1e-7) + fmaf(-2,r,1).
// Pipeline (validated): L1 = mfma 16x16x16f16 (bias k-slot 3 x packed 1.0);
// L2 = 2x mfma 16x16x32 (baked k-permutation); L3 = 2x mfma 16x16x32, w3 row 0.

typedef _Float16 f16x8 __attribute__((ext_vector_type(8)));
typedef _Float16 f16x4 __attribute__((ext_vector_type(4)));
typedef _Float16 f16x2 __attribute__((ext_vector_type(2)));
typedef float    f32x4 __attribute__((ext_vector_type(4)));
typedef unsigned int u32;
typedef u32 u32x2 __attribute__((ext_vector_type(2)));
typedef u32 u32x4 __attribute__((ext_vector_type(4)));

__device__ __forceinline__ u32 pk2u(float a, float b) {
#if __has_builtin(__builtin_amdgcn_cvt_pkrtz)
    return __builtin_bit_cast(u32, __builtin_amdgcn_cvt_pkrtz(a, b));
#else
    f16x2 p; p[0] = (_Float16)a; p[1] = (_Float16)b;
    return __builtin_bit_cast(u32, p);
#endif
}

__device__ __forceinline__ u32 pk_relu_cvt(float a, float b) {
    f16x2 p = __builtin_bit_cast(f16x2, pk2u(a, b));
    const f16x2 z = { (_Float16)0.0f, (_Float16)0.0f };
#if __has_builtin(__builtin_elementwise_max)
    p = __builtin_elementwise_max(p, z);
#else
    p[0] = p[0] > z[0] ? p[0] : z[0];
    p[1] = p[1] > z[1] ? p[1] : z[1];
#endif
    return __builtin_bit_cast(u32, p);
}

// tanh(o) from e = exp(2o): 1 - 2*rcp(e+1), rcp = v_rcp_f32 (1 ulp)
__device__ __forceinline__ float tanh_from_exp(float e) {
#if __has_builtin(__builtin_amdgcn_rcpf)
    const float r = __builtin_amdgcn_rcpf(e + 1.0f);
#else
    const float r = 1.0f / (e + 1.0f);
#endif
    return fmaf(-2.0f, r, 1.0f);
}

__global__ __launch_bounds__(256, 4) void nsde_kernel(
    const float* __restrict__ S0p, const float* __restrict__ Kp,
    const float* __restrict__ Tp,  const float* __restrict__ rfp,
    const float* __restrict__ V0p, const float* __restrict__ rhop,
    const float* __restrict__ Z1,  const float* __restrict__ Z2r,
    const float* __restrict__ W1,  const float* __restrict__ B1,
    const float* __restrict__ W2,  const float* __restrict__ B2,
    const float* __restrict__ W3,  const float* __restrict__ B3,
    float* __restrict__ out)
{
    __shared__ float nvp[2][4][64];   // [buf][net][element] = raw o, 2 KB
    __shared__ u32x2 pkx[4][64];      // [wave][element] {pk(S,V), pk(dt*s,1)}, 2 KB

    const int tid  = threadIdx.x;
    const int wave = tid >> 6;        // wave == net
    const int lane = tid & 63;
    const int q    = lane >> 4;
    const int mA   = lane & 15;
    const float rf = rfp[0];

    const float* w1g = W1 + wave * 256;   // [4][64]
    const float* b1g = B1 + wave * 64;
    const float* w2g = W2 + wave * 4096;  // [64][64] (h, g)
    const float* b2g = B2 + wave * 64;
    const float* w3g = W3 + wave * 64;    // [64]

    // ---------------- constant fragments (register-resident) ----------------
    // L1 (K=16): A[row=mA][k=q*4+j]; q==0 holds {wS, wV, wt, b1+rf*w_rf}.
    f16x4 A1[4];
    #pragma unroll
    for (int t = 0; t < 4; ++t) {
        f16x4 a = { (_Float16)0.0f, (_Float16)0.0f, (_Float16)0.0f, (_Float16)0.0f };
        if (q == 0) {
            const int h = t * 16 + mA;
            a[0] = (_Float16)w1g[0 * 64 + h];                       // S weight
            a[1] = (_Float16)w1g[1 * 64 + h];                       // V weight
            a[2] = (_Float16)w1g[3 * 64 + h];                       // dt*j weight
            a[3] = (_Float16)fmaf(rf, w1g[2 * 64 + h], b1g[h]);     // bias (x1.0)
        }
        A1[t] = a;
    }

    // L2 (K=32): A[row -> g=gt*16+mA][slot (kt,q*8+j) -> h1=H(kt,q*8+j)]
    f16x8 A2[4][2];
    #pragma unroll
    for (int gt = 0; gt < 4; ++gt)
        #pragma unroll
        for (int kt = 0; kt < 2; ++kt) {
            f16x8 a;
            #pragma unroll
            for (int j = 0; j < 8; ++j) {
                const int h1 = (2 * kt + (j >> 2)) * 16 + 4 * q + (j & 3);
                a[j] = (_Float16)w2g[h1 * 64 + gt * 16 + mA];
            }
            A2[gt][kt] = a;
        }

    // L3 (K=32 x2): row 0 = w3 (same baked permutation), other rows zero.
    f16x8 A3[2];
    #pragma unroll
    for (int kt = 0; kt < 2; ++kt) {
        f16x8 a;
        #pragma unroll
        for (int j = 0; j < 8; ++j) a[j] = (_Float16)0.0f;
        if (mA == 0) {
            #pragma unroll
            for (int j = 0; j < 8; ++j) {
                const int g = (2 * kt + (j >> 2)) * 16 + 4 * q + (j & 3);
                a[j] = (_Float16)w3g[g];
            }
        }
        A3[kt] = a;
    }

    // L2 bias C-splats (row = 4q+r); L1/L3 use zero C.
    f32x4 cinit2[4];
    #pragma unroll
    for (int t = 0; t < 4; ++t)
        #pragma unroll
        for (int r = 0; r < 4; ++r)
            cinit2[t][r] = b2g[t * 16 + 4 * q + r];
    const f32x4 zc = { 0.0f, 0.0f, 0.0f, 0.0f };

    // b3 per net (wave-uniform -> SGPRs), added in update phase.
    const float b3n0 = B3[0], b3n1 = B3[1], b3n2 = B3[2], b3n3 = B3[3];

    // ---------------- per-element state ----------------
    const int ebase = blockIdx.x * 64;
    const int d_own = (ebase + lane) & (D_OPT - 1);
    const float dt_own  = Tp[d_own] * (1.0f / (float)M_STEPS);
    const float sdt_own = sqrtf(dt_own);

    float Sreg = S0p[d_own];
    float Vreg = V0p[0];
    {
        u32x2 pk0;
        pk0[0] = pk2u(Sreg, Vreg);
        pk0[1] = pk2u(0.0f, 1.0f);    // {dt*j at step 0, bias multiplier}
        pkx[wave][lane] = pk0;
    }

    const float rho   = rhop[0];
    const float rho_c = sqrtf(1.0f - rho * rho);
    const size_t estep = (size_t)N_SIM * D_OPT;
    const float* z1p = Z1  + (size_t)ebase + (size_t)lane;
    const float* z2p = Z2r + (size_t)ebase + (size_t)lane;

    float z1c = *z1p;           // step 0 values
    float z2c = *z2p;
    z1p += estep; z2p += estep; // -> step 1

    #pragma unroll 1
    for (int s = 0; s < M_STEPS; ++s) {
        // prefetch next-step z (stays in flight across the lgkm-only barrier)
        const float z1n = *z1p;
        const float z2n = *z2p;
        const size_t adv = (s < M_STEPS - 2) ? estep : (size_t)0;
        z1p += adv; z2p += adv;

        #pragma unroll 2
        for (int mt = 0; mt < 4; ++mt) {
            // feature B-fragment = raw exchange word (zero VALU)
            const u32x2 pksv = pkx[wave][mt * 16 + mA];
            const f16x4 B1f = __builtin_bit_cast(f16x4, pksv);

            // L1 -> pack relu(h1) into B2 (adjacent acc pairs = baked slots)
            u32x4 b2u[2];
            #pragma unroll
            for (int t = 0; t < 4; ++t) {
                const f32x4 acc = __builtin_amdgcn_mfma_f32_16x16x16f16(
                                      A1[t], B1f, zc, 0, 0, 0);
                b2u[t >> 1][(t & 1) * 2 + 0] = pk_relu_cvt(acc[0], acc[1]);
                b2u[t >> 1][(t & 1) * 2 + 1] = pk_relu_cvt(acc[2], acc[3]);
            }
            const f16x8 B2f0 = __builtin_bit_cast(f16x8, b2u[0]);
            const f16x8 B2f1 = __builtin_bit_cast(f16x8, b2u[1]);

            // L2 -> pack relu(h2) into B3
            u32x4 b3u[2];
            #pragma unroll
            for (int gt = 0; gt < 4; ++gt) {
                f32x4 acc = __builtin_amdgcn_mfma_f32_16x16x32_f16(
                                A2[gt][0], B2f0, cinit2[gt], 0, 0, 0);
                acc = __builtin_amdgcn_mfma_f32_16x16x32_f16(
                                A2[gt][1], B2f1, acc, 0, 0, 0);
                b3u[gt >> 1][(gt & 1) * 2 + 0] = pk_relu_cvt(acc[0], acc[1]);
                b3u[gt >> 1][(gt & 1) * 2 + 1] = pk_relu_cvt(acc[2], acc[3]);
            }

            // L3: o lands in row 0 = lanes q==0, reg 0
            f32x4 acc3 = __builtin_amdgcn_mfma_f32_16x16x32_f16(
                             A3[0], __builtin_bit_cast(f16x8, b3u[0]), zc, 0, 0, 0);
            acc3 = __builtin_amdgcn_mfma_f32_16x16x32_f16(
                             A3[1], __builtin_bit_cast(f16x8, b3u[1]), acc3, 0, 0, 0);

            if (q == 0)
                nvp[s & 1][wave][mt * 16 + mA] = acc3[0];
        }

        // lgkm-only barrier: drain DS writes, sync waves, leave vmcnt in flight
        __builtin_amdgcn_sched_barrier(0);
        asm volatile("s_waitcnt lgkmcnt(0)\n\ts_barrier" ::: "memory");
        __builtin_amdgcn_sched_barrier(0);

        // ---- once-per-lane SDE update of own element e == lane ----
        {
            const float o0 = nvp[s & 1][0][lane] + b3n0;
            const float o1 = nvp[s & 1][1][lane] + b3n1;
            const float o2 = nvp[s & 1][2][lane] + b3n2;
            const float o3 = nvp[s & 1][3][lane] + b3n3;
            const float N0 = tanh_from_exp(__expf(2.0f * o0));
            const float N1 = tanh_from_exp(__expf(2.0f * o1));
            const float N2 = tanh_from_exp(__expf(2.0f * o2));
            const float N3 = tanh_from_exp(__expf(2.0f * o3));
            const float z2 = fmaf(rho, z1c, rho_c * z2c);
            const float fS = fmaf(N1 * sdt_own, z1c, N0 * dt_own);
            const float fV = fmaf(N3 * sdt_own, z2, N2 * dt_own);
            Sreg = fmaf(Sreg, fS, Sreg);
            Vreg = fmaf(Vreg, fV, Vreg);
            u32x2 pkn;
            pkn[0] = pk2u(Sreg, Vreg);
            pkn[1] = pk2u(dt_own * (float)(s + 1), 1.0f);  // next step's {dt*j, 1}
            pkx[wave][lane] = pkn;
            z1c = z1n; z2c = z2n;
        }
    }

    // ---- payoff: wave 0, lane == element ----
    if (wave == 0) {
        const float Td  = dt_own * (float)M_STEPS;
        const float pay = fmaxf(Sreg - Kp[d_own], 0.0f);
        atomicAdd(&out[d_own], __expf(-rf * Td) * pay * (1.0f / (float)N_SIM));
    }
}

extern "C" void kernel_launch(void* const* d_in, const int* in_sizes, int n_in,
                              void* d_out, int out_size, void* d_ws, size_t ws_size,
                              hipStream_t stream)
{
    const float* S0  = (const float*)d_in[0];
    const float* K   = (const float*)d_in[1];
    const float* T   = (const float*)d_in[2];
    const float* rf  = (const float*)d_in[3];
    const float* V0  = (const float*)d_in[4];
    const float* rho = (const float*)d_in[5];
    const float* Z1  = (const float*)d_in[6];
    const float* Z2r = (const float*)d_in[7];
    const float* W1  = (const float*)d_in[8];
    const float* B1  = (const float*)d_in[9];
    const float* W2  = (const float*)d_in[10];
    const float* B2  = (const float*)d_in[11];
    const float* W3  = (const float*)d_in[12];
    const float* B3  = (const float*)d_in[13];
    float* out = (float*)d_out;

    hipMemsetAsync(out, 0, (size_t)out_size * sizeof(float), stream);

    const int total = N_SIM * D_OPT;              // 262144 elements
    const int grid  = total / 64;                 // 64 elements per block
    nsde_kernel<<<grid, 256, 0, stream>>>(S0, K, T, rf, V0, rho, Z1, Z2r,
                                          W1, B1, W2, B2, W3, B3, out);
}